// Round 8
// baseline (118.599 us; speedup 1.0000x reference)
//
#include <hip/hip_runtime.h>

typedef __attribute__((ext_vector_type(4))) float f32x4;
typedef __attribute__((ext_vector_type(4))) int   i32x4;
typedef __attribute__((ext_vector_type(8))) short s16x8;

__device__ __forceinline__ unsigned short f2bf_rn(float f) {
  union { float f; unsigned u; } v; v.f = f;
  unsigned r = v.u + 0x7fffu + ((v.u >> 16) & 1u);
  return (unsigned short)(r >> 16);
}

__device__ __forceinline__ int packbf2(float lo, float hi) {
  union { float f; unsigned u; } a, b; a.f = lo; b.f = hi;
  return (int)__builtin_amdgcn_perm(b.u + 0x8000u, a.u + 0x8000u, 0x07060302u);
}

__device__ __forceinline__ void add8(i32x4 v, float g, f32x4& s0, f32x4& s1) {
  union { int ii; float ff; } u;
  u.ii = v[0] << 16;                  s0[0] = fmaf(g, u.ff, s0[0]);
  u.ii = v[0] & (int)0xffff0000u;     s0[1] = fmaf(g, u.ff, s0[1]);
  u.ii = v[1] << 16;                  s0[2] = fmaf(g, u.ff, s0[2]);
  u.ii = v[1] & (int)0xffff0000u;     s0[3] = fmaf(g, u.ff, s0[3]);
  u.ii = v[2] << 16;                  s1[0] = fmaf(g, u.ff, s1[0]);
  u.ii = v[2] & (int)0xffff0000u;     s1[1] = fmaf(g, u.ff, s1[1]);
  u.ii = v[3] << 16;                  s1[2] = fmaf(g, u.ff, s1[2]);
  u.ii = v[3] & (int)0xffff0000u;     s1[3] = fmaf(g, u.ff, s1[3]);
}

__device__ __forceinline__ void axis_cw(float p, int& il, int& ir, float& gl, float& gr) {
  float fl = floorf(p);
  float ql = fminf(fmaxf(fl, 0.f), 193.f);
  float qr = fminf(fmaxf(fl + 1.f, 0.f), 193.f);
  float pc = fminf(fmaxf(p, 0.f), 193.f);
  gl = 1.f + (ql - pc);
  gr = 1.f - (qr - pc);
  il = (int)ql; ir = (int)qr;
}

#define S_PAD (2 * 194 * 194 * 4)
#define NPAD_BLK 1177
#define NWF_BLK  9
#define NAM_BLK  288

// K0: three block-sections in one launch:
//  [0,1177)      NCHW fp32 -> zero-padded bf16 NHWC xp
//  [1177,1186)   conv_w -> bf16 MFMA B-fragments
//  [1186,1474)   Amap tiles: 16x16 pixels/block, x staged in LDS (fp32 conv)
__global__ __launch_bounds__(256) void k_prep(const float* __restrict__ x,
                                              unsigned short* __restrict__ xp,
                                              const float* __restrict__ w,
                                              short* __restrict__ wf,
                                              const float* __restrict__ p1w,
                                              const float* __restrict__ p1b,
                                              float* __restrict__ Amap) {
  __shared__ float xt[32 * 324];   // 18x18x32 fp32 tile (41.5 KB)
  __shared__ float wl[288];
  if (blockIdx.x < NPAD_BLK) {
    int t = blockIdx.x * 256 + threadIdx.x;
    if (t >= S_PAD) return;
    int pix = t >> 2, c8 = t & 3;
    int b = pix / (194 * 194);
    int r = pix % (194 * 194);
    int i = r / 194 - 1, j = r % 194 - 1;
    bool ok = ((unsigned)i < 192u) && ((unsigned)j < 192u);
    const float* src = x + (size_t)b * 32 * 36864 + (size_t)(c8 * 8) * 36864 + i * 192 + j;
    unsigned v[8];
    #pragma unroll
    for (int k = 0; k < 8; k++) v[k] = ok ? (unsigned)f2bf_rn(src[k * 36864]) : 0u;
    i32x4 pv;
    pv[0] = (int)(v[0] | (v[1] << 16));
    pv[1] = (int)(v[2] | (v[3] << 16));
    pv[2] = (int)(v[4] | (v[5] << 16));
    pv[3] = (int)(v[6] | (v[7] << 16));
    *(i32x4*)(xp + (size_t)pix * 32 + c8 * 8) = pv;
  } else if (blockIdx.x < NPAD_BLK + NWF_BLK) {
    int u = (blockIdx.x - NPAD_BLK) * 256 + threadIdx.x;
    if (u >= 9 * 4 * 64) return;
    int n = u / 256;
    int ot = (u / 64) % 4;
    int lane = u % 64;
    int o = ot * 16 + (lane & 15);
    int cb = (lane >> 4) * 8;
    #pragma unroll
    for (int jj = 0; jj < 8; jj++) {
      float v = w[(o * 32 + cb + jj) * 9 + n];
      wf[(size_t)u * 8 + jj] = (short)f2bf_rn(v);
    }
  } else {
    int tid = blockIdx.x - (NPAD_BLK + NWF_BLK);     // 0..287
    int b = tid / 144, rem = tid % 144;
    int i0 = (rem / 12) * 16, j0 = (rem % 12) * 16;
    for (int idx = threadIdx.x; idx < 288; idx += 256) wl[idx] = p1w[idx];
    const float* xb = x + (size_t)b * 32 * 36864;
    for (int idx = threadIdx.x; idx < 32 * 324; idx += 256) {
      int c = idx / 324, rr = (idx % 324) / 18, cc = idx % 18;
      int ii = i0 + rr - 1, jj = j0 + cc - 1;
      float v = (((unsigned)ii < 192u) && ((unsigned)jj < 192u))
                  ? xb[(size_t)c * 36864 + ii * 192 + jj] : 0.f;
      xt[idx] = v;
    }
    __syncthreads();
    int pr = threadIdx.x >> 4, pc = threadIdx.x & 15;
    float a0 = 0.f, a1 = 0.f, a2 = 0.f, a3 = 0.f;
    #pragma unroll
    for (int c = 0; c < 32; c += 4) {
      const float* b0 = xt + (c + 0) * 324;
      const float* b1 = xt + (c + 1) * 324;
      const float* b2 = xt + (c + 2) * 324;
      const float* b3 = xt + (c + 3) * 324;
      #pragma unroll
      for (int tap = 0; tap < 9; tap++) {
        int off = (pr + tap / 3) * 18 + pc + tap % 3;
        a0 = fmaf(b0[off], wl[(c + 0) * 9 + tap], a0);
        a1 = fmaf(b1[off], wl[(c + 1) * 9 + tap], a1);
        a2 = fmaf(b2[off], wl[(c + 2) * 9 + tap], a2);
        a3 = fmaf(b3[off], wl[(c + 3) * 9 + tap], a3);
      }
    }
    Amap[b * 36864 + (i0 + pr) * 192 + j0 + pc] = (a0 + a1) + (a2 + a3) + p1b[0];
  }
}

// K1: slim sampler: Amap load -> 4 axis_cw -> 9 steps, step-local loads at
// lookahead-1 (<=8 bufs live), 4 MFMAs/step. No LDS, no syncthreads.
__global__ __launch_bounds__(256, 5) void k_main(const unsigned short* __restrict__ xp,
                                                 const float* __restrict__ Amap,
                                                 const s16x8* __restrict__ wfv,
                                                 float* __restrict__ out) {
  int lane = threadIdx.x & 63;
  int bs = (blockIdx.x & 7) * 144 + (blockIdx.x >> 3);
  int W = bs * 4 + (threadIdx.x >> 6);
  int b = W / 2304;
  int r = W % 2304;
  int i = r / 12;
  int j0 = (r % 12) * 16;
  int m = lane & 15, quad = lane >> 4;
  int j = j0 + m;
  const unsigned short* xpb = xp + (size_t)b * (194 * 194 * 32) + quad * 8;
  float A = Amap[b * 36864 + i * 192 + j];

  float cx = (float)(i + 1), cy = (float)(j + 1);
  int icx = i + 1, icy = j + 1;

  int xlm, xrm, xlp, xrp, ylm, yrm, ylp, yrp;
  float gxlm, gxrm, gxlp, gxrp, gylm, gyrm, gylp, gyrp;
  axis_cw(cx - A, xlm, xrm, gxlm, gxrm);
  axis_cw(cx + A, xlp, xrp, gxlp, gxrp);
  axis_cw(cy - A, ylm, yrm, gylm, gyrm);
  axis_cw(cy + A, ylp, yrp, gylp, gyrp);

  int rT0 = xlm * 6208, rT1 = xrm * 6208;   // 194*32
  int rM  = icx * 6208;
  int rB0 = xlp * 6208, rB1 = xrp * 6208;
  int c0 = ylm * 32, c1 = yrm * 32, cC = icy * 32, c2 = ylp * 32, c3 = yrp * 32;

  f32x4 acc0 = {0.f, 0.f, 0.f, 0.f};
  f32x4 acc1 = acc0, acc2 = acc0, acc3 = acc0;

#define MFMA4(n, af)                                                              \
  { int wb = (n) * 256 + lane;                                                    \
    acc0 = __builtin_amdgcn_mfma_f32_16x16x32_bf16(af, wfv[wb],       acc0, 0, 0, 0); \
    acc1 = __builtin_amdgcn_mfma_f32_16x16x32_bf16(af, wfv[wb + 64],  acc1, 0, 0, 0); \
    acc2 = __builtin_amdgcn_mfma_f32_16x16x32_bf16(af, wfv[wb + 128], acc2, 0, 0, 0); \
    acc3 = __builtin_amdgcn_mfma_f32_16x16x32_bf16(af, wfv[wb + 192], acc3, 0, 0, 0); }

#define LD4(n, rA, rB, cL, cR)                                                    \
  i32x4 d##n##0 = *(const i32x4*)(xpb + (rA) + (cL));                             \
  i32x4 d##n##1 = *(const i32x4*)(xpb + (rB) + (cR));                             \
  i32x4 d##n##2 = *(const i32x4*)(xpb + (rA) + (cR));                             \
  i32x4 d##n##3 = *(const i32x4*)(xpb + (rB) + (cL));
#define LD2R(n, rA, rB, cc)                                                       \
  i32x4 d##n##0 = *(const i32x4*)(xpb + (rA) + (cc));                             \
  i32x4 d##n##1 = *(const i32x4*)(xpb + (rB) + (cc));
#define LD2C(n, rr, cL, cR)                                                       \
  i32x4 d##n##0 = *(const i32x4*)(xpb + (rr) + (cL));                             \
  i32x4 d##n##1 = *(const i32x4*)(xpb + (rr) + (cR));
#define LD1(n, rr, cc)                                                            \
  i32x4 d##n##0 = *(const i32x4*)(xpb + (rr) + (cc));

#define PACK_GO(n, s0, s1)                                                        \
  { s16x8 af; int* ai = (int*)&af;                                                \
    ai[0] = packbf2(s0[0], s0[1]); ai[1] = packbf2(s0[2], s0[3]);                 \
    ai[2] = packbf2(s1[0], s1[1]); ai[3] = packbf2(s1[2], s1[3]);                 \
    MFMA4(n, af) }

#define P4(n, gxL, gxR, gyL, gyR)                                                 \
  { f32x4 s0 = {0.f, 0.f, 0.f, 0.f}, s1 = s0;                                     \
    add8(d##n##0, (gxL) * (gyL), s0, s1);                                         \
    add8(d##n##1, (gxR) * (gyR), s0, s1);                                         \
    add8(d##n##2, (gxL) * (gyR), s0, s1);                                         \
    add8(d##n##3, (gxR) * (gyL), s0, s1);                                         \
    PACK_GO(n, s0, s1) }

#define P2(n, gL, gR)                                                             \
  { f32x4 s0 = {0.f, 0.f, 0.f, 0.f}, s1 = s0;                                     \
    add8(d##n##0, (gL), s0, s1);                                                  \
    add8(d##n##1, (gR), s0, s1);                                                  \
    PACK_GO(n, s0, s1) }

  LD4(0, rT0, rT1, c0, c1)
  LD2R(1, rT0, rT1, cC)
  P4(0, gxlm, gxrm, gylm, gyrm)
  LD4(2, rT0, rT1, c2, c3)
  P2(1, gxlm, gxrm)
  LD2C(3, rM, c0, c1)
  P4(2, gxlm, gxrm, gylp, gyrp)
  LD1(4, rM, cC)
  P2(3, gylm, gyrm)
  LD2C(5, rM, c2, c3)
  {  // center: exact integer coords — fragment is a bitcast of the bf16 line
    s16x8 af; int* ai = (int*)&af;
    ai[0] = d40[0]; ai[1] = d40[1]; ai[2] = d40[2]; ai[3] = d40[3];
    MFMA4(4, af)
  }
  LD4(6, rB0, rB1, c0, c1)
  P2(5, gylp, gyrp)
  LD2R(7, rB0, rB1, cC)
  P4(6, gxlp, gxrp, gylm, gyrm)
  LD4(8, rB0, rB1, c2, c3)
  P2(7, gxlp, gxrp)
  P4(8, gxlp, gxrp, gylp, gyrp)

#undef LD4
#undef LD2R
#undef LD2C
#undef LD1
#undef P4
#undef P2
#undef PACK_GO
#undef MFMA4

  int o0 = lane & 15;
  int jout = j0 + quad * 4;
  float* op = out + (size_t)b * 64 * 36864 + (size_t)o0 * 36864 + i * 192 + jout;
  *(f32x4*)(op) = acc0;
  *(f32x4*)(op + 16 * 36864) = acc1;
  *(f32x4*)(op + 32 * 36864) = acc2;
  *(f32x4*)(op + 48 * 36864) = acc3;
}

extern "C" void kernel_launch(void* const* d_in, const int* in_sizes, int n_in,
                              void* d_out, int out_size, void* d_ws, size_t ws_size,
                              hipStream_t stream) {
  const float* x      = (const float*)d_in[0];
  const float* conv_w = (const float*)d_in[1];
  const float* p1w    = (const float*)d_in[4];
  const float* p1b    = (const float*)d_in[5];
  float* out = (float*)d_out;

  unsigned short* xp = (unsigned short*)d_ws;       // 2*194*194*32 bf16
  short* wf   = (short*)(xp + 2 * 194 * 194 * 32);  // 9*256*8 bf16
  float* Amap = (float*)(wf + 9 * 256 * 8);         // 73,728 fp32

  k_prep<<<NPAD_BLK + NWF_BLK + NAM_BLK, 256, 0, stream>>>(x, xp, conv_w, wf,
                                                           p1w, p1b, Amap);
  k_main<<<1152, 256, 0, stream>>>(xp, Amap, (const s16x8*)wf, out);
}

// Round 10
// 97.275 us; speedup vs baseline: 1.2192x; 1.2192x over previous
//
#include <hip/hip_runtime.h>

typedef __attribute__((ext_vector_type(4))) float f32x4;
typedef __attribute__((ext_vector_type(4))) int   i32x4;
typedef __attribute__((ext_vector_type(8))) short s16x8;

__device__ __forceinline__ unsigned short f2bf_rn(float f) {
  union { float f; unsigned u; } v; v.f = f;
  unsigned r = v.u + 0x7fffu + ((v.u >> 16) & 1u);
  return (unsigned short)(r >> 16);
}

// pack two fp32 -> two bf16 (round-half-up) in one int via v_perm_b32
__device__ __forceinline__ int packbf2(float lo, float hi) {
  union { float f; unsigned u; } a, b; a.f = lo; b.f = hi;
  return (int)__builtin_amdgcn_perm(b.u + 0x8000u, a.u + 0x8000u, 0x07060302u);
}

// unpack 8 bf16 (i32x4) and accumulate g*x into s0(ch0..3), s1(ch4..7)
__device__ __forceinline__ void add8(i32x4 v, float g, f32x4& s0, f32x4& s1) {
  union { int ii; float ff; } u;
  u.ii = v[0] << 16;                  s0[0] = fmaf(g, u.ff, s0[0]);
  u.ii = v[0] & (int)0xffff0000u;     s0[1] = fmaf(g, u.ff, s0[1]);
  u.ii = v[1] << 16;                  s0[2] = fmaf(g, u.ff, s0[2]);
  u.ii = v[1] & (int)0xffff0000u;     s0[3] = fmaf(g, u.ff, s0[3]);
  u.ii = v[2] << 16;                  s1[0] = fmaf(g, u.ff, s1[0]);
  u.ii = v[2] & (int)0xffff0000u;     s1[1] = fmaf(g, u.ff, s1[1]);
  u.ii = v[3] << 16;                  s1[2] = fmaf(g, u.ff, s1[2]);
  u.ii = v[3] & (int)0xffff0000u;     s1[3] = fmaf(g, u.ff, s1[3]);
}

__device__ __forceinline__ void axis_cw(float p, int& il, int& ir, float& gl, float& gr) {
  float fl = floorf(p);
  float ql = fminf(fmaxf(fl, 0.f), 193.f);
  float qr = fminf(fmaxf(fl + 1.f, 0.f), 193.f);
  float pc = fminf(fmaxf(p, 0.f), 193.f);
  gl = 1.f + (ql - pc);
  gr = 1.f - (qr - pc);
  il = (int)ql; ir = (int)qr;
}

#define S_PAD (2 * 194 * 194 * 4)
#define S_WF  (9 * 4 * 64)

// K0 merged: NCHW fp32 -> zero-padded bf16 NHWC xp, plus conv_w -> B-fragments.
__global__ __launch_bounds__(256) void k_prep(const float* __restrict__ x,
                                              unsigned short* __restrict__ xp,
                                              const float* __restrict__ w,
                                              short* __restrict__ wf) {
  int t = blockIdx.x * 256 + threadIdx.x;
  if (t < S_PAD) {
    int pix = t >> 2, c8 = t & 3;
    int b = pix / (194 * 194);
    int r = pix % (194 * 194);
    int i = r / 194 - 1, j = r % 194 - 1;
    bool ok = ((unsigned)i < 192u) && ((unsigned)j < 192u);
    const float* src = x + (size_t)b * 32 * 36864 + (size_t)(c8 * 8) * 36864 + i * 192 + j;
    unsigned v[8];
    #pragma unroll
    for (int k = 0; k < 8; k++) v[k] = ok ? (unsigned)f2bf_rn(src[k * 36864]) : 0u;
    i32x4 pv;
    pv[0] = (int)(v[0] | (v[1] << 16));
    pv[1] = (int)(v[2] | (v[3] << 16));
    pv[2] = (int)(v[4] | (v[5] << 16));
    pv[3] = (int)(v[6] | (v[7] << 16));
    *(i32x4*)(xp + (size_t)pix * 32 + c8 * 8) = pv;
  } else {
    int u = t - S_PAD;
    if (u >= S_WF) return;
    int n = u / 256;
    int ot = (u / 64) % 4;
    int lane = u % 64;
    int o = ot * 16 + (lane & 15);
    int cb = (lane >> 4) * 8;
    #pragma unroll
    for (int jj = 0; jj < 8; jj++) {
      float v = w[(o * 32 + cb + jj) * 9 + n];
      wf[(size_t)u * 8 + jj] = (short)f2bf_rn(v);
    }
  }
}

// K1: split-step wave pairing. 2 waves per 16-pixel segment partition the
// A-conv taps and the 9 sampling steps; LDS reduce; half0 stores.
__global__ __launch_bounds__(256, 4) void k_main(const unsigned short* __restrict__ xp,
                                                 const float* __restrict__ p1w,
                                                 const float* __restrict__ p1b,
                                                 const s16x8* __restrict__ wfv,
                                                 float* __restrict__ out) {
  __shared__ float wlds[288];          // p1w reordered: wlds[tap*32 + c]
  __shared__ float redA[2][2][16];     // [pair][half][pixel]
  __shared__ float redC[2][64][17];    // [pair][lane][16+1 pad]
  for (int idx = threadIdx.x; idx < 288; idx += 256) {
    int c = idx / 9, tap = idx % 9;
    wlds[tap * 32 + c] = p1w[idx];
  }
  __syncthreads();

  int lane = threadIdx.x & 63;
  int wid  = threadIdx.x >> 6;
  int pair = wid >> 1, half = wid & 1;
  // XCD swizzle: 2304 blocks = 8 XCDs x 288 contiguous; 2 segments/block.
  int bs = (blockIdx.x & 7) * 288 + (blockIdx.x >> 3);
  int seg = bs * 2 + pair;
  int b = seg / 2304;
  int r = seg % 2304;
  int i = r / 12;
  int j0 = (r % 12) * 16;
  int m = lane & 15, quad = lane >> 4;
  int j = j0 + m;
  const unsigned short* xpb = xp + (size_t)b * (194 * 194 * 32) + quad * 8;

  // ---- A-conv partial: half0 taps 0..4 (keeps center line), half1 taps 5..8.
  float a0 = 0.f, a1 = 0.f, a2 = 0.f, a3 = 0.f;
  i32x4 vcen = {0, 0, 0, 0};
#define ATAP(tap)                                                              \
  { i32x4 v = *(const i32x4*)(xpb + ((i + (tap) / 3) * 194 + (j + (tap) % 3)) * 32); \
    if ((tap) == 4) vcen = v;                                                  \
    const f32x4* wp = (const f32x4*)(wlds + (tap) * 32 + quad * 8);            \
    f32x4 w0 = wp[0], w1 = wp[1];                                              \
    union { int ii; float ff; } u;                                             \
    u.ii = v[0] << 16;              a0 = fmaf(u.ff, w0[0], a0);                \
    u.ii = v[0] & (int)0xffff0000u; a1 = fmaf(u.ff, w0[1], a1);                \
    u.ii = v[1] << 16;              a2 = fmaf(u.ff, w0[2], a2);                \
    u.ii = v[1] & (int)0xffff0000u; a3 = fmaf(u.ff, w0[3], a3);                \
    u.ii = v[2] << 16;              a0 = fmaf(u.ff, w1[0], a0);                \
    u.ii = v[2] & (int)0xffff0000u; a1 = fmaf(u.ff, w1[1], a1);                \
    u.ii = v[3] << 16;              a2 = fmaf(u.ff, w1[2], a2);                \
    u.ii = v[3] & (int)0xffff0000u; a3 = fmaf(u.ff, w1[3], a3); }
  if (half == 0) {
    ATAP(0) ATAP(1) ATAP(2) ATAP(3) ATAP(4)
  } else {
    ATAP(5) ATAP(6) ATAP(7) ATAP(8)
  }
#undef ATAP
  float a = (a0 + a1) + (a2 + a3);
  a += __shfl_xor(a, 16);
  a += __shfl_xor(a, 32);
  if (lane < 16) redA[pair][half][lane] = a;
  __syncthreads();
  float A = redA[pair][0][m] + redA[pair][1][m] + p1b[0];

  float cx = (float)(i + 1), cy = (float)(j + 1);
  int icx = i + 1, icy = j + 1;
  int rM = icx * 6208;  // 194*32

  int ylm, yrm, ylp, yrp;
  float gylm, gyrm, gylp, gyrp;
  axis_cw(cy - A, ylm, yrm, gylm, gyrm);
  axis_cw(cy + A, ylp, yrp, gylp, gyrp);
  int c0 = ylm * 32, c1 = yrm * 32, cC = icy * 32, c2 = ylp * 32, c3 = yrp * 32;

  f32x4 acc0 = {0.f, 0.f, 0.f, 0.f};
  f32x4 acc1 = acc0, acc2 = acc0, acc3 = acc0;

#define MFMA4(n, af)                                                              \
  { int wb = (n) * 256 + lane;                                                    \
    acc0 = __builtin_amdgcn_mfma_f32_16x16x32_bf16(af, wfv[wb],       acc0, 0, 0, 0); \
    acc1 = __builtin_amdgcn_mfma_f32_16x16x32_bf16(af, wfv[wb + 64],  acc1, 0, 0, 0); \
    acc2 = __builtin_amdgcn_mfma_f32_16x16x32_bf16(af, wfv[wb + 128], acc2, 0, 0, 0); \
    acc3 = __builtin_amdgcn_mfma_f32_16x16x32_bf16(af, wfv[wb + 192], acc3, 0, 0, 0); }

#define PROC4(n, dLT, dRB, dLB, dRT, gx_l, gx_r, gy_l, gy_r)                      \
  { f32x4 s0 = {0.f, 0.f, 0.f, 0.f}, s1 = s0;                                     \
    add8(dLT, (gx_l) * (gy_l), s0, s1);                                           \
    add8(dRB, (gx_r) * (gy_r), s0, s1);                                           \
    add8(dLB, (gx_l) * (gy_r), s0, s1);                                           \
    add8(dRT, (gx_r) * (gy_l), s0, s1);                                           \
    s16x8 af; int* ai = (int*)&af;                                                \
    ai[0] = packbf2(s0[0], s0[1]); ai[1] = packbf2(s0[2], s0[3]);                 \
    ai[2] = packbf2(s1[0], s1[1]); ai[3] = packbf2(s1[2], s1[3]);                 \
    MFMA4(n, af) }

#define PROC2(n, dL, dR, g_l, g_r)                                                \
  { f32x4 s0 = {0.f, 0.f, 0.f, 0.f}, s1 = s0;                                     \
    add8(dL, (g_l), s0, s1);                                                      \
    add8(dR, (g_r), s0, s1);                                                      \
    s16x8 af; int* ai = (int*)&af;                                                \
    ai[0] = packbf2(s0[0], s0[1]); ai[1] = packbf2(s0[2], s0[3]);                 \
    ai[2] = packbf2(s1[0], s1[1]); ai[3] = packbf2(s1[2], s1[3]);                 \
    MFMA4(n, af) }

  if (half == 0) {
    // rows xlm,xrm (dx=-1) x 5 cols + M cols c0,c1; steps 0,1,2,3,center.
    int xlm, xrm; float gxlm, gxrm;
    axis_cw(cx - A, xlm, xrm, gxlm, gxrm);
    int rT0 = xlm * 6208, rT1 = xrm * 6208;
    i32x4 T00 = *(const i32x4*)(xpb + rT0 + c0);
    i32x4 T01 = *(const i32x4*)(xpb + rT0 + c1);
    i32x4 T0C = *(const i32x4*)(xpb + rT0 + cC);
    i32x4 T02 = *(const i32x4*)(xpb + rT0 + c2);
    i32x4 T03 = *(const i32x4*)(xpb + rT0 + c3);
    i32x4 T10 = *(const i32x4*)(xpb + rT1 + c0);
    i32x4 T11 = *(const i32x4*)(xpb + rT1 + c1);
    i32x4 T1C = *(const i32x4*)(xpb + rT1 + cC);
    i32x4 T12 = *(const i32x4*)(xpb + rT1 + c2);
    i32x4 T13 = *(const i32x4*)(xpb + rT1 + c3);
    i32x4 M0  = *(const i32x4*)(xpb + rM + c0);
    i32x4 M1  = *(const i32x4*)(xpb + rM + c1);
    PROC4(0, T00, T11, T01, T10, gxlm, gxrm, gylm, gyrm)
    PROC2(1, T0C, T1C, gxlm, gxrm)
    PROC4(2, T02, T13, T03, T12, gxlm, gxrm, gylp, gyrp)
    PROC2(3, M0, M1, gylm, gyrm)
    { s16x8 af; int* ai = (int*)&af;
      ai[0] = vcen[0]; ai[1] = vcen[1]; ai[2] = vcen[2]; ai[3] = vcen[3];
      MFMA4(4, af) }
  } else {
    // M cols c2,c3 + rows xlp,xrp (dx=+1) x 5 cols; steps 5,6,7,8.
    int xlp, xrp; float gxlp, gxrp;
    axis_cw(cx + A, xlp, xrp, gxlp, gxrp);
    int rB0 = xlp * 6208, rB1 = xrp * 6208;
    i32x4 M2  = *(const i32x4*)(xpb + rM + c2);
    i32x4 M3  = *(const i32x4*)(xpb + rM + c3);
    i32x4 B00 = *(const i32x4*)(xpb + rB0 + c0);
    i32x4 B01 = *(const i32x4*)(xpb + rB0 + c1);
    i32x4 B0C = *(const i32x4*)(xpb + rB0 + cC);
    i32x4 B02 = *(const i32x4*)(xpb + rB0 + c2);
    i32x4 B03 = *(const i32x4*)(xpb + rB0 + c3);
    i32x4 B10 = *(const i32x4*)(xpb + rB1 + c0);
    i32x4 B11 = *(const i32x4*)(xpb + rB1 + c1);
    i32x4 B1C = *(const i32x4*)(xpb + rB1 + cC);
    i32x4 B12 = *(const i32x4*)(xpb + rB1 + c2);
    i32x4 B13 = *(const i32x4*)(xpb + rB1 + c3);
    PROC2(5, M2, M3, gylp, gyrp)
    PROC4(6, B00, B11, B01, B10, gxlp, gxrp, gylm, gyrm)
    PROC2(7, B0C, B1C, gxlp, gxrp)
    PROC4(8, B02, B13, B03, B12, gxlp, gxrp, gylp, gyrp)
  }
#undef PROC4
#undef PROC2
#undef MFMA4

  // ---- pair reduction: half1 -> LDS, half0 adds and stores.
  if (half == 1) {
    f32x4* dst = (f32x4*)&redC[pair][lane][0];
    dst[0] = acc0; dst[1] = acc1; dst[2] = acc2; dst[3] = acc3;
  }
  __syncthreads();
  if (half == 0) {
    const float* src = &redC[pair][lane][0];
    const f32x4* sv = (const f32x4*)src;
    acc0 += sv[0]; acc1 += sv[1]; acc2 += sv[2]; acc3 += sv[3];
    int o0 = lane & 15;
    int jout = j0 + quad * 4;
    float* op = out + (size_t)b * 64 * 36864 + (size_t)o0 * 36864 + i * 192 + jout;
    *(f32x4*)(op) = acc0;
    *(f32x4*)(op + 16 * 36864) = acc1;
    *(f32x4*)(op + 32 * 36864) = acc2;
    *(f32x4*)(op + 48 * 36864) = acc3;
  }
}

extern "C" void kernel_launch(void* const* d_in, const int* in_sizes, int n_in,
                              void* d_out, int out_size, void* d_ws, size_t ws_size,
                              hipStream_t stream) {
  const float* x      = (const float*)d_in[0];
  const float* conv_w = (const float*)d_in[1];
  const float* p1w    = (const float*)d_in[4];
  const float* p1b    = (const float*)d_in[5];
  float* out = (float*)d_out;

  unsigned short* xp = (unsigned short*)d_ws;     // 2*194*194*32 bf16
  short* wf = (short*)(xp + 2 * 194 * 194 * 32);  // 9*256*8 bf16

  int prep_threads = S_PAD + S_WF;
  k_prep<<<(prep_threads + 255) / 256, 256, 0, stream>>>(x, xp, conv_w, wf);
  k_main<<<2304, 256, 0, stream>>>(xp, p1w, p1b, (const s16x8*)wf, out);
}